// Round 11
// baseline (457.816 us; speedup 1.0000x reference)
//
#include <hip/hip_runtime.h>
#include <hip/hip_bf16.h>

using bf16 = __hip_bfloat16;
typedef __attribute__((ext_vector_type(8))) short bf16x8;
typedef __attribute__((ext_vector_type(4))) float f32x4;

#define DDIM 1024

__device__ __forceinline__ void gload16(const bf16* g, bf16* l) {
    __builtin_amdgcn_global_load_lds(
        (const __attribute__((address_space(1))) void*)g,
        (__attribute__((address_space(3))) void*)l, 16, 0, 0);
}
__device__ __forceinline__ short f2b(float f) {
    return (short)__bfloat16_as_ushort(__float2bfloat16(f));
}

__global__ void prep_kernel(const float* __restrict__ W, const float* __restrict__ w,
                            const float* __restrict__ b, const float* __restrict__ nstr,
                            const float* __restrict__ nraw,
                            float* __restrict__ dco, float* __restrict__ ad2,
                            bf16* __restrict__ Wb) {
    int o = blockIdx.x;
    int lane = threadIdx.x;
    const float* Wrow = W + (size_t)o * DDIM;
    bf16* Wbrow = Wb + (size_t)o * DDIM;
    float s = 0.f;
    for (int j = lane; j < DDIM; j += 64) {
        float wv = Wrow[j];
        Wbrow[j] = __float2bfloat16(wv);
        float m = wv * w[j];
        s += m * m;
    }
#pragma unroll
    for (int off = 32; off; off >>= 1) s += __shfl_down(s, off);
    if (lane == 0) {
        dco[o] = rsqrtf(s + 1e-8f);
        ad2[o] = nraw[o] * nstr[0] + b[o];
    }
}

// ---- 256x256x(BK=64) 8-phase GEMM, C[n][o] = sum_j A[n][j]*W[o][j] ----
// R8 exactly, plus sched_barrier(0) pins at phase boundaries: raw s_barrier has NO
// scheduling semantics in LLVM, so without pins the compiler may sink the phase's
// ds_reads past the barrier, serializing each phase (read-latency + MFMA back-to-back).
#define SBAR() __builtin_amdgcn_sched_barrier(0)
#define BAR()  __builtin_amdgcn_s_barrier()
#define VMW(n) asm volatile("s_waitcnt vmcnt(" #n ")")
#define LGW()  asm volatile("s_waitcnt lgkmcnt(0)")
// phase-boundary barrier: pin issue-block before, compute-block after
#define BARP() do { SBAR(); BAR(); SBAR(); } while (0)

template<int PASS>
__global__ __launch_bounds__(512, 2) void gemm8p(
    const float* __restrict__ Af, const bf16* __restrict__ Ab,
    const bf16* __restrict__ Bw,
    const float* __restrict__ wst, const float* __restrict__ bias,
    const float* __restrict__ dco, const float* __restrict__ ad2,
    bf16* __restrict__ Cb, float* __restrict__ Cf)
{
    __shared__ bf16 sA[2][2][256 * 32];   // 64 KiB
    __shared__ bf16 sB[2][2][256 * 32];   // 64 KiB

    const int tid  = threadIdx.x;
    const int lane = tid & 63;
    const int wid  = tid >> 6;
    const int wr   = wid >> 2, wc = wid & 3;      // 2 x 4 waves
    const int r16  = lane & 15, kh = lane >> 4;
    const int fso  = (kh ^ ((r16 >> 1) & 3)) * 8; // swizzled frag slot (elems)

    int bx  = blockIdx.x;                          // 1024 blocks
    int swz = (bx & 7) * 128 + (bx >> 3);          // bijective XCD swizzle
    int brow = swz >> 2, bcol = swz & 3;

    const float* Asrc_f = Af + (size_t)(brow * 256) * DDIM;
    const bf16*  Asrc_b = Ab + (size_t)(brow * 256) * DDIM;
    const bf16*  Bsrc   = Bw + (size_t)(bcol * 256) * DDIM;

    const int sr  = tid >> 2;                      // staging row 0..127 (and +128)
    const int ssl = (tid & 3) ^ ((sr >> 1) & 3);   // swizzled 16B source slot

    f32x4 acc[8][4];
#pragma unroll
    for (int m = 0; m < 8; ++m)
#pragma unroll
        for (int n = 0; n < 4; ++n) acc[m][n] = (f32x4){0.f, 0.f, 0.f, 0.f};

    bf16x8 aF[4], bF[4];
    float4 gA0, gA1, gA2, gA3;   // PASS1 A-prefetch regs (K-half 0 group)
    float4 gB0, gB1, gB2, gB3;   // PASS1 A-prefetch regs (K-half 1 group)

#define STAGE_B(buf, kt, ks) do { \
    const bf16* _s = Bsrc + (size_t)sr * DDIM + ((kt) * 64 + (ks) * 32 + ssl * 8); \
    gload16(_s,               &sB[buf][ks][tid * 8]); \
    gload16(_s + 128 * DDIM,  &sB[buf][ks][(tid + 512) * 8]); \
} while (0)

#define STAGE_A_G(buf, kt, ks) do { \
    const bf16* _s = Asrc_b + (size_t)sr * DDIM + ((kt) * 64 + (ks) * 32 + ssl * 8); \
    gload16(_s,               &sA[buf][ks][tid * 8]); \
    gload16(_s + 128 * DDIM,  &sA[buf][ks][(tid + 512) * 8]); \
} while (0)

#define LOAD_A_F(g0, g1, g2, g3, kt, ks) do { \
    const float* _p = Asrc_f + (size_t)sr * DDIM + ((kt) * 64 + (ks) * 32 + (tid & 3) * 8); \
    g0 = ((const float4*)_p)[0]; g1 = ((const float4*)_p)[1]; \
    const float* _q = _p + 128 * DDIM; \
    g2 = ((const float4*)_q)[0]; g3 = ((const float4*)_q)[1]; \
} while (0)

#define WRITE_A(buf, ks, g0, g1, g2, g3) do { \
    bf16x8 _pk; \
    _pk[0]=f2b(g0.x); _pk[1]=f2b(g0.y); _pk[2]=f2b(g0.z); _pk[3]=f2b(g0.w); \
    _pk[4]=f2b(g1.x); _pk[5]=f2b(g1.y); _pk[6]=f2b(g1.z); _pk[7]=f2b(g1.w); \
    *(bf16x8*)&sA[buf][ks][sr * 32 + ssl * 8] = _pk; \
    _pk[0]=f2b(g2.x); _pk[1]=f2b(g2.y); _pk[2]=f2b(g2.z); _pk[3]=f2b(g2.w); \
    _pk[4]=f2b(g3.x); _pk[5]=f2b(g3.y); _pk[6]=f2b(g3.z); _pk[7]=f2b(g3.w); \
    *(bf16x8*)&sA[buf][ks][(sr + 128) * 32 + ssl * 8] = _pk; \
} while (0)

#define RD_A(buf, ks, mh) do { \
    _Pragma("unroll") for (int _m = 0; _m < 4; ++_m) \
        aF[_m] = *(const bf16x8*)&sA[buf][ks][(wr * 128 + (mh) * 64 + _m * 16 + r16) * 32 + fso]; \
} while (0)

#define RD_B(buf, ks) do { \
    _Pragma("unroll") for (int _n = 0; _n < 4; ++_n) \
        bF[_n] = *(const bf16x8*)&sB[buf][ks][(wc * 64 + _n * 16 + r16) * 32 + fso]; \
} while (0)

#define MFMA16(mh) do { \
    __builtin_amdgcn_s_setprio(1); \
    _Pragma("unroll") for (int _m = 0; _m < 4; ++_m) { \
        acc[(mh)*4+_m][0] = __builtin_amdgcn_mfma_f32_16x16x32_bf16(aF[_m], bF[0], acc[(mh)*4+_m][0], 0, 0, 0); \
        acc[(mh)*4+_m][1] = __builtin_amdgcn_mfma_f32_16x16x32_bf16(aF[_m], bF[1], acc[(mh)*4+_m][1], 0, 0, 0); \
        acc[(mh)*4+_m][2] = __builtin_amdgcn_mfma_f32_16x16x32_bf16(aF[_m], bF[2], acc[(mh)*4+_m][2], 0, 0, 0); \
        acc[(mh)*4+_m][3] = __builtin_amdgcn_mfma_f32_16x16x32_bf16(aF[_m], bF[3], acc[(mh)*4+_m][3], 0, 0, 0); \
    } \
    __builtin_amdgcn_s_setprio(0); \
} while (0)

    // ---------------- prologue ----------------
    if constexpr (PASS == 1) {
        LOAD_A_F(gA0, gA1, gA2, gA3, 0, 0);
        LOAD_A_F(gB0, gB1, gB2, gB3, 0, 1);
        STAGE_B(0, 0, 0); STAGE_B(0, 0, 1);
        WRITE_A(0, 0, gA0, gA1, gA2, gA3);
        WRITE_A(0, 1, gB0, gB1, gB2, gB3);
        LOAD_A_F(gA0, gA1, gA2, gA3, 1, 0);    // consumed at ph0 (t1.AK0)
        LOAD_A_F(gB0, gB1, gB2, gB3, 1, 1);    // consumed at ph2 (t1.AK1)
        LGW();
        VMW(8);                                 // retire t0.B halves; LA groups in flight
        BARP();
    } else {
        STAGE_A_G(0, 0, 0); STAGE_B(0, 0, 0);
        STAGE_A_G(0, 0, 1); STAGE_B(0, 0, 1);
        VMW(4);                                 // t0.K0 landed; t0.K1 in flight
        BARP();
    }

    // ---------------- main loop: 8 iters x 2 K-tiles ----------------
    for (int i = 0; i < 8; ++i) {
        int t1 = 2 * i + 1;
        int t2 = 2 * i + 2; if (t2 > 15) t2 = 15;   // tail clamp (stages never read)
        int t3 = 2 * i + 3; if (t3 > 15) t3 = 15;

        // ph0: compute (t0 buf0, ks0, mh0); stage t1.AK0 -> buf1
        RD_A(0, 0, 0); RD_B(0, 0);
        if constexpr (PASS == 1) {
            WRITE_A(1, 0, gA0, gA1, gA2, gA3);
            LOAD_A_F(gA0, gA1, gA2, gA3, t2, 0);
            LGW();
        } else {
            STAGE_A_G(1, t1, 0);
        }
        BARP(); MFMA16(0); BARP();

        // ph1: (ks0, mh1); stage t1.BK0 -> buf1
        RD_A(0, 0, 1);
        STAGE_B(1, t1, 0);
        BARP(); MFMA16(1); SBAR();
        if constexpr (PASS == 1) { VMW(6); } else { VMW(4); }
        BARP();

        // ph2: (ks1, mh0); stage t1.AK1 -> buf1
        RD_A(0, 1, 0); RD_B(0, 1);
        if constexpr (PASS == 1) {
            WRITE_A(1, 1, gB0, gB1, gB2, gB3);
            LOAD_A_F(gB0, gB1, gB2, gB3, t2, 1);
            LGW();
        } else {
            STAGE_A_G(1, t1, 1);
        }
        BARP(); MFMA16(0); BARP();

        // ph3: (ks1, mh1); stage t1.BK1 -> buf1
        RD_A(0, 1, 1);
        STAGE_B(1, t1, 1);
        BARP(); MFMA16(1); SBAR();
        if constexpr (PASS == 1) { VMW(6); } else { VMW(4); }
        BARP();

        // ph4: compute (t1 buf1, ks0, mh0); stage t2.AK0 -> buf0
        RD_A(1, 0, 0); RD_B(1, 0);
        if constexpr (PASS == 1) {
            WRITE_A(0, 0, gA0, gA1, gA2, gA3);
            LOAD_A_F(gA0, gA1, gA2, gA3, t3, 0);
            LGW();
        } else {
            STAGE_A_G(0, t2, 0);
        }
        BARP(); MFMA16(0); BARP();

        // ph5: (ks0, mh1); stage t2.BK0 -> buf0
        RD_A(1, 0, 1);
        STAGE_B(0, t2, 0);
        BARP(); MFMA16(1); SBAR();
        if constexpr (PASS == 1) { VMW(6); } else { VMW(4); }
        BARP();

        // ph6: (ks1, mh0); stage t2.AK1 -> buf0
        RD_A(1, 1, 0); RD_B(1, 1);
        if constexpr (PASS == 1) {
            WRITE_A(0, 1, gB0, gB1, gB2, gB3);
            LOAD_A_F(gB0, gB1, gB2, gB3, t3, 1);
            LGW();
        } else {
            STAGE_A_G(0, t2, 1);
        }
        BARP(); MFMA16(0); BARP();

        // ph7: (ks1, mh1); stage t2.BK1 -> buf0
        RD_A(1, 1, 1);
        STAGE_B(0, t2, 1);
        BARP(); MFMA16(1); SBAR();
        if constexpr (PASS == 1) { VMW(6); } else { VMW(4); }
        BARP();
    }

    // ---------------- epilogue ----------------
    int crb = brow * 256 + wr * 128 + kh * 4;
    int ccb = bcol * 256 + wc * 64 + r16;
#pragma unroll
    for (int n = 0; n < 4; ++n) {
        int col = ccb + n * 16;
        float cm, ca;
        if constexpr (PASS == 1) { cm = wst[col]; ca = bias[col]; }
        else                     { cm = dco[col]; ca = ad2[col]; }
#pragma unroll
        for (int m = 0; m < 8; ++m) {
#pragma unroll
            for (int j = 0; j < 4; ++j) {
                size_t idx = (size_t)(crb + m * 16 + j) * DDIM + col;
                float v = acc[m][n][j];
                if constexpr (PASS == 1) {
                    v = (v + ca) * cm;
                    Cb[idx] = __float2bfloat16(v);
                } else {
                    v = v * cm + ca;
                    v = (v >= 0.f) ? v : 0.01f * v;
                    Cf[idx] = v;
                }
            }
        }
    }
#undef STAGE_B
#undef STAGE_A_G
#undef LOAD_A_F
#undef WRITE_A
#undef RD_A
#undef RD_B
#undef MFMA16
}

extern "C" void kernel_launch(void* const* d_in, const int* in_sizes, int n_in,
                              void* d_out, int out_size, void* d_ws, size_t ws_size,
                              hipStream_t stream) {
    const float* x  = (const float*)d_in[0];
    const float* w  = (const float*)d_in[1];
    const float* W  = (const float*)d_in[2];
    const float* b  = (const float*)d_in[3];
    const float* ns = (const float*)d_in[4];
    const float* nr = (const float*)d_in[5];
    float* out = (float*)d_out;

    float* dco = (float*)d_ws;
    float* ad2 = dco + DDIM;
    bf16*  Wb  = (bf16*)((char*)d_ws + 8192);
    bf16*  t   = (bf16*)((char*)d_ws + 8192 + 2097152);

    int M = in_sizes[0] / DDIM;                     // 65536
    int grid = (M / 256) * (DDIM / 256);            // 1024

    prep_kernel<<<DDIM, 64, 0, stream>>>(W, w, b, ns, nr, dco, ad2, Wb);
    gemm8p<1><<<grid, 512, 0, stream>>>(x, nullptr, Wb, w, b, dco, ad2, t, nullptr);
    gemm8p<2><<<grid, 512, 0, stream>>>(nullptr, t, Wb, w, b, dco, ad2, nullptr, out);
}

// Round 12
// 295.079 us; speedup vs baseline: 1.5515x; 1.5515x over previous
//
#include <hip/hip_runtime.h>
#include <hip/hip_bf16.h>

using bf16 = __hip_bfloat16;
typedef __attribute__((ext_vector_type(8))) short bf16x8;
typedef __attribute__((ext_vector_type(4))) float f32x4;

#define DDIM 1024

__device__ __forceinline__ void gload16(const bf16* g, bf16* l) {
    __builtin_amdgcn_global_load_lds(
        (const __attribute__((address_space(1))) void*)g,
        (__attribute__((address_space(3))) void*)l, 16, 0, 0);
}
__device__ __forceinline__ short f2b(float f) {
    return (short)__bfloat16_as_ushort(__float2bfloat16(f));
}

// Fusion: out = lrelu((x @ Mt^T) * dco + add)
//   Mt[o,k] = sum_j (W[o,j]*w[j]) * W[j,k]   (precomputed, bf16)
//   dco[o]  = rsqrt(sum_j (W[o,j]*w[j])^2 + 1e-8)
//   add[o]  = (sum_j b[j]*w[j]*W[o,j])*dco[o] + nraw[o]*ns + b[o]

// prep: per row o -> dco, add, Qb[o,k] = bf16(W[o,k]*w[k])
__global__ void prep_kernel(const float* __restrict__ W, const float* __restrict__ w,
                            const float* __restrict__ b, const float* __restrict__ nstr,
                            const float* __restrict__ nraw,
                            float* __restrict__ dco, float* __restrict__ add,
                            bf16* __restrict__ Qb) {
    int o = blockIdx.x;
    int lane = threadIdx.x;
    const float* Wrow = W + (size_t)o * DDIM;
    bf16* Qrow = Qb + (size_t)o * DDIM;
    float s = 0.f, c = 0.f;
    for (int j = lane; j < DDIM; j += 64) {
        float wv = Wrow[j], sv = w[j];
        float q = wv * sv;
        Qrow[j] = __float2bfloat16(q);
        s += q * q;
        c += b[j] * q;
    }
#pragma unroll
    for (int off = 32; off; off >>= 1) {
        s += __shfl_down(s, off);
        c += __shfl_down(c, off);
    }
    if (lane == 0) {
        float d = rsqrtf(s + 1e-8f);
        dco[o] = d;
        add[o] = c * d + nraw[o] * nstr[0] + b[o];
    }
}

// Wt[k][j] = bf16(W[j][k])  (64x64 LDS tiles)
__global__ void transpose_kernel(const float* __restrict__ W, bf16* __restrict__ Wt) {
    __shared__ bf16 tile[64][72];          // +8 pad
    int bi = blockIdx.x * 64;              // source row block (j)
    int bj = blockIdx.y * 64;              // source col block (k)
    int r  = threadIdx.x >> 2;             // 0..63
    int c4 = (threadIdx.x & 3) * 16;       // 0/16/32/48
    const float* src = W + (size_t)(bi + r) * DDIM + bj + c4;
#pragma unroll
    for (int i = 0; i < 16; ++i) tile[r][c4 + i] = __float2bfloat16(src[i]);
    __syncthreads();
    bf16* dst = Wt + (size_t)(bj + r) * DDIM + bi + c4;   // Wt[bj+r][bi+c] = tile[c][r]
#pragma unroll
    for (int i = 0; i < 16; ++i) dst[i] = tile[c4 + i][r];
}

// Mt[m][n] = sum_k Qb[m][k] * Wt[n][k]; 1024^3, 128x128 tile, grid 64. Simple R2-style.
__global__ __launch_bounds__(256) void mgemm(const bf16* __restrict__ A,
                                             const bf16* __restrict__ B,
                                             bf16* __restrict__ C) {
    __shared__ bf16 lA[128 * 32];
    __shared__ bf16 lB[128 * 32];
    int tid  = threadIdx.x;
    int lane = tid & 63, wid = tid >> 6;
    int wr = wid >> 1, wc = wid & 1;
    int brow = blockIdx.x >> 3;            // 8x8 blocks, direct map
    int bcol = blockIdx.x & 7;

    const bf16* Ab = A + (size_t)brow * 128 * DDIM;
    const bf16* Bb = B + (size_t)bcol * 128 * DDIM;
    int srow = tid >> 2;
    int scol = (tid & 3) * 8;

    f32x4 acc[4][4];
#pragma unroll
    for (int m = 0; m < 4; ++m)
#pragma unroll
        for (int n = 0; n < 4; ++n) acc[m][n] = (f32x4){0.f, 0.f, 0.f, 0.f};

    int r16 = lane & 15, kh = lane >> 4;

    for (int k0 = 0; k0 < DDIM; k0 += 32) {
        gload16(Ab + (size_t)srow * DDIM + k0 + scol,        lA + tid * 8);
        gload16(Ab + (size_t)(srow + 64) * DDIM + k0 + scol, lA + (tid + 256) * 8);
        gload16(Bb + (size_t)srow * DDIM + k0 + scol,        lB + tid * 8);
        gload16(Bb + (size_t)(srow + 64) * DDIM + k0 + scol, lB + (tid + 256) * 8);
        __syncthreads();
        bf16x8 aF[4], bF[4];
#pragma unroll
        for (int m = 0; m < 4; ++m) {
            aF[m] = *(const bf16x8*)(lA + ((wr * 64 + m * 16 + r16) * 32 + kh * 8));
            bF[m] = *(const bf16x8*)(lB + ((wc * 64 + m * 16 + r16) * 32 + kh * 8));
        }
#pragma unroll
        for (int m = 0; m < 4; ++m)
#pragma unroll
            for (int n = 0; n < 4; ++n)
                acc[m][n] = __builtin_amdgcn_mfma_f32_16x16x32_bf16(aF[m], bF[n], acc[m][n], 0, 0, 0);
        __syncthreads();
    }

    int cb = lane & 15;
    int rb = (lane >> 4) * 4;
#pragma unroll
    for (int n = 0; n < 4; ++n) {
        int col = bcol * 128 + wc * 64 + n * 16 + cb;
#pragma unroll
        for (int m = 0; m < 4; ++m)
#pragma unroll
            for (int j = 0; j < 4; ++j) {
                int row = wr * 64 + m * 16 + rb + j;
                C[((size_t)brow * 128 + row) * DDIM + col] = __float2bfloat16(acc[m][n][j]);
            }
    }
}

// ---- big GEMM: out[n][o] = lrelu(dco[o] * sum_j x[n,j]*Mt[o,j] + add[o]) ----
// R8 PASS1 structure verbatim (256x256, 8 waves, 8-phase, reg-staged fp32 A,
// gload_lds B, VMW(6) ledger) with the fused epilogue.
#define BAR()  __builtin_amdgcn_s_barrier()
#define VMW(n) asm volatile("s_waitcnt vmcnt(" #n ")")
#define LGW()  asm volatile("s_waitcnt lgkmcnt(0)")

__global__ __launch_bounds__(512, 2) void big_gemm(
    const float* __restrict__ Af, const bf16* __restrict__ Bw,
    const float* __restrict__ dco, const float* __restrict__ add,
    float* __restrict__ Cf)
{
    __shared__ bf16 sA[2][2][256 * 32];   // 64 KiB
    __shared__ bf16 sB[2][2][256 * 32];   // 64 KiB

    const int tid  = threadIdx.x;
    const int lane = tid & 63;
    const int wid  = tid >> 6;
    const int wr   = wid >> 2, wc = wid & 3;      // 2 x 4 waves
    const int r16  = lane & 15, kh = lane >> 4;
    const int fso  = (kh ^ ((r16 >> 1) & 3)) * 8; // swizzled frag slot (elems)

    int bx  = blockIdx.x;                          // 1024 blocks
    int swz = (bx & 7) * 128 + (bx >> 3);          // bijective XCD swizzle
    int brow = swz >> 2, bcol = swz & 3;

    const float* Asrc_f = Af + (size_t)(brow * 256) * DDIM;
    const bf16*  Bsrc   = Bw + (size_t)(bcol * 256) * DDIM;

    const int sr  = tid >> 2;                      // staging row 0..127 (and +128)
    const int ssl = (tid & 3) ^ ((sr >> 1) & 3);   // swizzled 16B source slot

    f32x4 acc[8][4];
#pragma unroll
    for (int m = 0; m < 8; ++m)
#pragma unroll
        for (int n = 0; n < 4; ++n) acc[m][n] = (f32x4){0.f, 0.f, 0.f, 0.f};

    bf16x8 aF[4], bF[4];
    float4 gA0, gA1, gA2, gA3;   // A-prefetch regs (K-half 0 group)
    float4 gB0, gB1, gB2, gB3;   // A-prefetch regs (K-half 1 group)

#define STAGE_B(buf, kt, ks) do { \
    const bf16* _s = Bsrc + (size_t)sr * DDIM + ((kt) * 64 + (ks) * 32 + ssl * 8); \
    gload16(_s,               &sB[buf][ks][tid * 8]); \
    gload16(_s + 128 * DDIM,  &sB[buf][ks][(tid + 512) * 8]); \
} while (0)

#define LOAD_A_F(g0, g1, g2, g3, kt, ks) do { \
    const float* _p = Asrc_f + (size_t)sr * DDIM + ((kt) * 64 + (ks) * 32 + (tid & 3) * 8); \
    g0 = ((const float4*)_p)[0]; g1 = ((const float4*)_p)[1]; \
    const float* _q = _p + 128 * DDIM; \
    g2 = ((const float4*)_q)[0]; g3 = ((const float4*)_q)[1]; \
} while (0)

#define WRITE_A(buf, ks, g0, g1, g2, g3) do { \
    bf16x8 _pk; \
    _pk[0]=f2b(g0.x); _pk[1]=f2b(g0.y); _pk[2]=f2b(g0.z); _pk[3]=f2b(g0.w); \
    _pk[4]=f2b(g1.x); _pk[5]=f2b(g1.y); _pk[6]=f2b(g1.z); _pk[7]=f2b(g1.w); \
    *(bf16x8*)&sA[buf][ks][sr * 32 + ssl * 8] = _pk; \
    _pk[0]=f2b(g2.x); _pk[1]=f2b(g2.y); _pk[2]=f2b(g2.z); _pk[3]=f2b(g2.w); \
    _pk[4]=f2b(g3.x); _pk[5]=f2b(g3.y); _pk[6]=f2b(g3.z); _pk[7]=f2b(g3.w); \
    *(bf16x8*)&sA[buf][ks][(sr + 128) * 32 + ssl * 8] = _pk; \
} while (0)

#define RD_A(buf, ks, mh) do { \
    _Pragma("unroll") for (int _m = 0; _m < 4; ++_m) \
        aF[_m] = *(const bf16x8*)&sA[buf][ks][(wr * 128 + (mh) * 64 + _m * 16 + r16) * 32 + fso]; \
} while (0)

#define RD_B(buf, ks) do { \
    _Pragma("unroll") for (int _n = 0; _n < 4; ++_n) \
        bF[_n] = *(const bf16x8*)&sB[buf][ks][(wc * 64 + _n * 16 + r16) * 32 + fso]; \
} while (0)

#define MFMA16(mh) do { \
    __builtin_amdgcn_s_setprio(1); \
    _Pragma("unroll") for (int _m = 0; _m < 4; ++_m) { \
        acc[(mh)*4+_m][0] = __builtin_amdgcn_mfma_f32_16x16x32_bf16(aF[_m], bF[0], acc[(mh)*4+_m][0], 0, 0, 0); \
        acc[(mh)*4+_m][1] = __builtin_amdgcn_mfma_f32_16x16x32_bf16(aF[_m], bF[1], acc[(mh)*4+_m][1], 0, 0, 0); \
        acc[(mh)*4+_m][2] = __builtin_amdgcn_mfma_f32_16x16x32_bf16(aF[_m], bF[2], acc[(mh)*4+_m][2], 0, 0, 0); \
        acc[(mh)*4+_m][3] = __builtin_amdgcn_mfma_f32_16x16x32_bf16(aF[_m], bF[3], acc[(mh)*4+_m][3], 0, 0, 0); \
    } \
    __builtin_amdgcn_s_setprio(0); \
} while (0)

    // prologue (R8 PASS1)
    LOAD_A_F(gA0, gA1, gA2, gA3, 0, 0);
    LOAD_A_F(gB0, gB1, gB2, gB3, 0, 1);
    STAGE_B(0, 0, 0); STAGE_B(0, 0, 1);
    WRITE_A(0, 0, gA0, gA1, gA2, gA3);
    WRITE_A(0, 1, gB0, gB1, gB2, gB3);
    LOAD_A_F(gA0, gA1, gA2, gA3, 1, 0);
    LOAD_A_F(gB0, gB1, gB2, gB3, 1, 1);
    LGW();
    VMW(8);
    BAR();

    for (int i = 0; i < 8; ++i) {
        int t2 = 2 * i + 2; if (t2 > 15) t2 = 15;
        int t3 = 2 * i + 3; if (t3 > 15) t3 = 15;
        int t1 = 2 * i + 1;

        // ph0
        RD_A(0, 0, 0); RD_B(0, 0);
        WRITE_A(1, 0, gA0, gA1, gA2, gA3);
        LOAD_A_F(gA0, gA1, gA2, gA3, t2, 0);
        LGW();
        BAR(); MFMA16(0); BAR();
        // ph1
        RD_A(0, 0, 1);
        STAGE_B(1, t1, 0);
        BAR(); MFMA16(1); VMW(6); BAR();
        // ph2
        RD_A(0, 1, 0); RD_B(0, 1);
        WRITE_A(1, 1, gB0, gB1, gB2, gB3);
        LOAD_A_F(gB0, gB1, gB2, gB3, t2, 1);
        LGW();
        BAR(); MFMA16(0); BAR();
        // ph3
        RD_A(0, 1, 1);
        STAGE_B(1, t1, 1);
        BAR(); MFMA16(1); VMW(6); BAR();
        // ph4
        RD_A(1, 0, 0); RD_B(1, 0);
        WRITE_A(0, 0, gA0, gA1, gA2, gA3);
        LOAD_A_F(gA0, gA1, gA2, gA3, t3, 0);
        LGW();
        BAR(); MFMA16(0); BAR();
        // ph5
        RD_A(1, 0, 1);
        STAGE_B(0, t2, 0);
        BAR(); MFMA16(1); VMW(6); BAR();
        // ph6
        RD_A(1, 1, 0); RD_B(1, 1);
        WRITE_A(0, 1, gB0, gB1, gB2, gB3);
        LOAD_A_F(gB0, gB1, gB2, gB3, t3, 1);
        LGW();
        BAR(); MFMA16(0); BAR();
        // ph7
        RD_A(1, 1, 1);
        STAGE_B(0, t2, 1);
        BAR(); MFMA16(1); VMW(6); BAR();
    }

    // fused epilogue: v = acc*dco[col] + add[col]; leaky-relu; fp32 out
    int crb = brow * 256 + wr * 128 + kh * 4;
    int ccb = bcol * 256 + wc * 64 + r16;
#pragma unroll
    for (int n = 0; n < 4; ++n) {
        int col = ccb + n * 16;
        float cm = dco[col], ca = add[col];
#pragma unroll
        for (int m = 0; m < 8; ++m) {
#pragma unroll
            for (int j = 0; j < 4; ++j) {
                size_t idx = (size_t)(crb + m * 16 + j) * DDIM + col;
                float v = acc[m][n][j] * cm + ca;
                v = (v >= 0.f) ? v : 0.01f * v;
                Cf[idx] = v;
            }
        }
    }
#undef STAGE_B
#undef LOAD_A_F
#undef WRITE_A
#undef RD_A
#undef RD_B
#undef MFMA16
}

extern "C" void kernel_launch(void* const* d_in, const int* in_sizes, int n_in,
                              void* d_out, int out_size, void* d_ws, size_t ws_size,
                              hipStream_t stream) {
    const float* x  = (const float*)d_in[0];
    const float* w  = (const float*)d_in[1];
    const float* W  = (const float*)d_in[2];
    const float* b  = (const float*)d_in[3];
    const float* ns = (const float*)d_in[4];
    const float* nr = (const float*)d_in[5];
    float* out = (float*)d_out;

    float* dco = (float*)d_ws;                                   // 4 KB
    float* add = dco + DDIM;                                     // 4 KB
    bf16*  Qb  = (bf16*)((char*)d_ws + 8192);                    // 2 MB
    bf16*  Wt  = (bf16*)((char*)d_ws + 8192 + 2097152);          // 2 MB
    bf16*  Mt  = (bf16*)((char*)d_ws + 8192 + 2 * 2097152);      // 2 MB

    int M = in_sizes[0] / DDIM;                                  // 65536
    int grid = (M / 256) * (DDIM / 256);                         // 1024

    prep_kernel<<<DDIM, 64, 0, stream>>>(W, w, b, ns, nr, dco, add, Qb);
    transpose_kernel<<<dim3(16, 16), 256, 0, stream>>>(W, Wt);
    mgemm<<<64, 256, 0, stream>>>(Qb, Wt, Mt);
    big_gemm<<<grid, 512, 0, stream>>>(x, Mt, dco, add, out);
}